// Round 3
// baseline (1355.720 us; speedup 1.0000x reference)
//
#include <hip/hip_runtime.h>
#include <hip/hip_bf16.h>
#include <stdint.h>

#define N_NODES 32768
#define N_EDGES 262144

typedef __attribute__((ext_vector_type(8))) short short8;
typedef __attribute__((ext_vector_type(4))) float f32x4;

__device__ __forceinline__ float bf2f(ushort u) {
  return __uint_as_float(((uint)u) << 16);
}
__device__ __forceinline__ ushort f2bf(float f) {
  uint x = __float_as_uint(f);
  uint r = (x + 0x7fffu + ((x >> 16) & 1u)) >> 16;
  return (ushort)r;
}

// Load element i of a float array whose storage is bf16 (isbf=1) or fp32 (isbf=0).
__device__ __forceinline__ float loadf(const void* p, size_t i, int isbf) {
  return isbf ? bf2f(((const ushort*)p)[i]) : ((const float*)p)[i];
}

__device__ __forceinline__ void atomicMaxFloat(float* addr, float val) {
  if (val >= 0.f) atomicMax((int*)addr, __float_as_int(val));
  else atomicMin((unsigned int*)addr, (unsigned int)__float_as_int(val));
}

// ---------------- dtype detection ----------------
// bf16-packed N(0,1) data: low-16-bit "exponent" field in [0x60,0x90] almost surely.
// fp32 data: low 16 bits are mantissa bits -> uniform (~19% hit rate).
__global__ void detect_dtype(const uint* __restrict__ xw, int* __restrict__ flag) {
  __shared__ int cnt;
  if (threadIdx.x == 0) cnt = 0;
  __syncthreads();
  int good = 0;
  for (int i = threadIdx.x; i < 1024; i += 256) {
    uint lo = xw[i] & 0xFFFFu;
    uint ef = (lo >> 7) & 0xFFu;
    if (lo == 0u || (ef >= 0x60u && ef <= 0x90u)) good++;
  }
  atomicAdd(&cnt, good);
  __syncthreads();
  if (threadIdx.x == 0) *flag = (cnt >= 614) ? 1 : 0;
}

// ---------------- setup kernels (flag-aware input reads) ----------------
__global__ void setup_small(const void* __restrict__ ba, const void* __restrict__ bn,
                            const void* __restrict__ aw, const int* __restrict__ flag,
                            float* __restrict__ bias2, float* __restrict__ bnf,
                            float* __restrict__ wf) {
  int fl = *flag;
  int t = blockIdx.x * blockDim.x + threadIdx.x;   // 1024 threads
  if (t < 1024) bias2[t] = (t < 512) ? loadf(ba, t, fl) : 0.f;
  if (t < 512) { bnf[t] = loadf(bn, t, fl); wf[t] = loadf(aw, t, fl); }
}

__global__ void build_wnt(const void* __restrict__ Wn, const int* __restrict__ flag,
                          ushort* __restrict__ WnpT) {
  int fl = *flag;
  int t = blockIdx.x * blockDim.x + threadIdx.x;   // 512*128
  int n = t >> 7, k = t & 127;
  WnpT[t] = (k < 118) ? f2bf(loadf(Wn, (size_t)k * 512 + n, fl)) : (ushort)0;
}

__global__ void build_xp(const void* __restrict__ x, const int* __restrict__ flag,
                         ushort* __restrict__ xp) {
  int fl = *flag;
  int t = blockIdx.x * blockDim.x + threadIdx.x;   // 32768*128
  int i = t >> 7, k = t & 127;
  xp[t] = (k < 118) ? f2bf(loadf(x, (size_t)i * 118 + k, fl)) : (ushort)0;
}

// W2T[n][k] (1024 x 512, row-major): W2[k][j] = j<512 ? Wa[k][j] : Wa[512+k][j-512]
__global__ void build_w2t(const void* __restrict__ Wa, const int* __restrict__ flag,
                          ushort* __restrict__ W2T) {
  int fl = *flag;
  int t = blockIdx.x * blockDim.x + threadIdx.x;   // 1024*512
  int n = t >> 9, k = t & 511;
  size_t idx = (n < 512) ? ((size_t)k * 512 + n) : ((size_t)(512 + k) * 512 + (n - 512));
  W2T[t] = f2bf(loadf(Wa, idx, fl));
}

__global__ void fill_md(float* __restrict__ mmax, float* __restrict__ denom) {
  int t = blockIdx.x * blockDim.x + threadIdx.x;   // 32768*8
  mmax[t] = -3e38f;
  denom[t] = 0.f;
}

// ---------------- GEMM: C[M,N](bf16) = A[M,K](bf16) @ B + bias; BT = B^T [N,K] ----------------
// 128x128 block tile, 4 waves (2x2 of 64x64), BK=32, 16x16x32 bf16 MFMA, register staging.
__global__ __launch_bounds__(256)
void gemm_bf16(const ushort* __restrict__ A, const ushort* __restrict__ BT,
               const float* __restrict__ bias, ushort* __restrict__ C,
               int M, int N, int K) {
  __shared__ __align__(16) ushort As[128 * 32];
  __shared__ __align__(16) ushort Bs[128 * 32];
  const int tid = threadIdx.x, wave = tid >> 6, lane = tid & 63;
  const int bm = blockIdx.y * 128, bn = blockIdx.x * 128;
  const int wm = (wave >> 1) * 64, wn = (wave & 1) * 64;
  const int fcol = lane & 15, quad = lane >> 4;

  const f32x4 zero = {0.f, 0.f, 0.f, 0.f};
  f32x4 acc[4][4];
#pragma unroll
  for (int i = 0; i < 4; ++i)
#pragma unroll
    for (int j = 0; j < 4; ++j) acc[i][j] = zero;

  for (int k0 = 0; k0 < K; k0 += 32) {
#pragma unroll
    for (int r = 0; r < 2; ++r) {
      int o = r * 4096 + wave * 1024 + lane * 16;   // byte offset in 128x32 tile
      int row = o >> 6;                              // 64 B per tile row
      int ke = (o & 63) >> 1;
      short8 va = *(const short8*)(A + (size_t)(bm + row) * K + k0 + ke);
      short8 vb = *(const short8*)(BT + (size_t)(bn + row) * K + k0 + ke);
      *(short8*)&As[o >> 1] = va;
      *(short8*)&Bs[o >> 1] = vb;
    }
    __syncthreads();
    short8 a[4], b[4];
#pragma unroll
    for (int i = 0; i < 4; ++i) {
      a[i] = *(const short8*)&As[(wm + i * 16 + fcol) * 32 + quad * 8];
      b[i] = *(const short8*)&Bs[(wn + i * 16 + fcol) * 32 + quad * 8];
    }
#pragma unroll
    for (int i = 0; i < 4; ++i)
#pragma unroll
      for (int j = 0; j < 4; ++j)
        acc[i][j] = __builtin_amdgcn_mfma_f32_16x16x32_bf16(a[i], b[j], acc[i][j], 0, 0, 0);
    __syncthreads();
  }

  // epilogue: C/D layout col=lane&15, row=quad*4+reg
#pragma unroll
  for (int i = 0; i < 4; ++i) {
    int rowb = bm + wm + i * 16 + quad * 4;
#pragma unroll
    for (int j = 0; j < 4; ++j) {
      int col = bn + wn + j * 16 + fcol;
      float bb = bias[col];
#pragma unroll
      for (int r = 0; r < 4; ++r) {
        C[(size_t)(rowb + r) * N + col] = f2bf(acc[i][j][r] + bb);
      }
    }
  }
}

// ---------------- edge pass A: score + segment max ----------------
__global__ __launch_bounds__(256)
void edge_score(const ushort* __restrict__ PQ, const int* __restrict__ src,
                const int* __restrict__ dst, const float* __restrict__ wf,
                float* __restrict__ score, float* __restrict__ mmax) {
  const int wave = threadIdx.x >> 6, lane = threadIdx.x & 63;
  const int e = blockIdx.x * 4 + wave;
  const int s = src[e], d = dst[e];
  const int c0 = lane * 8;
  const uint4 pu = *(const uint4*)(PQ + (size_t)s * 1024 + c0);
  const uint4 qu = *(const uint4*)(PQ + (size_t)d * 1024 + 512 + c0);
  const float4 w0 = *(const float4*)(wf + c0);
  const float4 w1 = *(const float4*)(wf + c0 + 4);
  const uint pw[4] = {pu.x, pu.y, pu.z, pu.w};
  const uint qw[4] = {qu.x, qu.y, qu.z, qu.w};
  const float wv[8] = {w0.x, w0.y, w0.z, w0.w, w1.x, w1.y, w1.z, w1.w};
  float part = 0.f;
#pragma unroll
  for (int w = 0; w < 4; ++w) {
    float pa = __uint_as_float(pw[w] << 16);
    float pb = __uint_as_float(pw[w] & 0xffff0000u);
    float qa = __uint_as_float(qw[w] << 16);
    float qb = __uint_as_float(qw[w] & 0xffff0000u);
    float ea = pa + qa; ea = (ea > 0.f) ? ea : 0.01f * ea;
    float eb = pb + qb; eb = (eb > 0.f) ? eb : 0.01f * eb;
    part += ea * wv[2 * w] + eb * wv[2 * w + 1];
  }
  part += __shfl_xor(part, 1);
  part += __shfl_xor(part, 2);
  part += __shfl_xor(part, 4);
  if ((lane & 7) == 0) {
    int h = lane >> 3;
    score[(size_t)e * 8 + h] = part;
    atomicMaxFloat(&mmax[(size_t)d * 8 + h], part);
  }
}

// ---------------- edge pass B: ex = exp(s - m[dst]); denom += ex ----------------
__global__ __launch_bounds__(256)
void edge_exp(const int* __restrict__ dst, const float* __restrict__ mmax,
              float* __restrict__ score, float* __restrict__ denom) {
  int t = blockIdx.x * blockDim.x + threadIdx.x;   // E*8
  int e = t >> 3, h = t & 7;
  int d = dst[e];
  float ex = expf(score[t] - mmax[(size_t)d * 8 + h]);
  score[t] = ex;
  unsafeAtomicAdd(&denom[(size_t)d * 8 + h], ex);
}

// ---------------- edge pass C: h_new[dst] += h[src] * alpha ----------------
__global__ __launch_bounds__(256)
void edge_msg(const ushort* __restrict__ hb, const int* __restrict__ src,
              const int* __restrict__ dst, const float* __restrict__ score,
              const float* __restrict__ denom, float* __restrict__ hacc) {
  const int wave = threadIdx.x >> 6, lane = threadIdx.x & 63;
  const int e = blockIdx.x * 4 + wave;
  const int s = src[e], d = dst[e];
  float a8 = 0.f;
  if (lane < 8) a8 = score[(size_t)e * 8 + lane] / denom[(size_t)d * 8 + lane];
  const ushort* hrow = hb + (size_t)s * 512;
  float* orow = hacc + (size_t)d * 512;
#pragma unroll
  for (int r = 0; r < 8; ++r) {
    float alpha = __shfl(a8, r);
    int c = r * 64 + lane;
    unsafeAtomicAdd(&orow[c], bf2f(hrow[c]) * alpha);
  }
}

// ---------------- convert fp32 accumulator -> bf16 hb (+ final output, dtype per flag) ----------
__global__ __launch_bounds__(256)
void convert_h(const float* __restrict__ hacc, const int* __restrict__ flag,
               ushort* __restrict__ hb, void* __restrict__ out, int write_out) {
  int fl = *flag;
  int t = blockIdx.x * blockDim.x + threadIdx.x;   // 32768*512
  float v = hacc[t];
  hb[t] = f2bf(v);
  if (write_out) {
    if (fl) ((ushort*)out)[t] = f2bf(v);
    else    ((float*)out)[t] = v;
  }
}

extern "C" void kernel_launch(void* const* d_in, const int* in_sizes, int n_in,
                              void* d_out, int out_size, void* d_ws, size_t ws_size,
                              hipStream_t stream) {
  const void* x   = d_in[0];
  const int*  src = (const int*)d_in[2];
  const int*  dst = (const int*)d_in[3];
  const void* Wn  = d_in[4];
  const void* bn  = d_in[5];
  const void* Wa  = d_in[8];
  const void* ba  = d_in[9];
  const void* aw  = d_in[10];

  char* ws = (char*)d_ws;
  size_t off = 0;
  auto alloc = [&](size_t bytes) {
    char* p = ws + off;
    off = (off + bytes + 255) & ~(size_t)255;
    return p;
  };
  ushort* hb    = (ushort*)alloc((size_t)N_NODES * 512 * 2);
  // PQ (bf16 [N,1024]) and hacc (f32 [N,512]) are both 64 MB, disjoint lifetimes -> alias.
  char*   pqh   = alloc((size_t)N_NODES * 1024 * 2);
  ushort* PQ    = (ushort*)pqh;
  float*  hacc  = (float*)pqh;
  float*  score = (float*) alloc((size_t)N_EDGES * 8 * 4);
  float*  mmax  = (float*) alloc((size_t)N_NODES * 8 * 4);
  float*  denom = (float*) alloc((size_t)N_NODES * 8 * 4);
  ushort* W2T   = (ushort*)alloc((size_t)1024 * 512 * 2);
  float*  bias2 = (float*) alloc(1024 * 4);
  ushort* xp    = (ushort*)alloc((size_t)N_NODES * 128 * 2);
  ushort* WnpT  = (ushort*)alloc((size_t)512 * 128 * 2);
  float*  bnf   = (float*) alloc(512 * 4);
  float*  wf    = (float*) alloc(512 * 4);
  int*    flag  = (int*)   alloc(256);

  detect_dtype<<<1, 256, 0, stream>>>((const uint*)x, flag);
  setup_small<<<4, 256, 0, stream>>>(ba, bn, aw, flag, bias2, bnf, wf);
  build_wnt<<<(512 * 128) / 256, 256, 0, stream>>>(Wn, flag, WnpT);
  build_xp<<<(N_NODES * 128) / 256, 256, 0, stream>>>(x, flag, xp);
  build_w2t<<<(1024 * 512) / 256, 256, 0, stream>>>(Wa, flag, W2T);

  // h0 = x @ Wn + bn   (K padded 118 -> 128)
  {
    dim3 g(512 / 128, N_NODES / 128);
    gemm_bf16<<<g, 256, 0, stream>>>(xp, WnpT, bnf, hb, N_NODES, 512, 128);
  }

  for (int layer = 0; layer < 2; ++layer) {
    dim3 g(1024 / 128, N_NODES / 128);
    gemm_bf16<<<g, 256, 0, stream>>>(hb, W2T, bias2, PQ, N_NODES, 1024, 512);
    fill_md<<<(N_NODES * 8) / 256, 256, 0, stream>>>(mmax, denom);
    edge_score<<<N_EDGES / 4, 256, 0, stream>>>(PQ, src, dst, wf, score, mmax);
    edge_exp<<<(N_EDGES * 8) / 256, 256, 0, stream>>>(dst, mmax, score, denom);
    // PQ dead; reuse its storage as the fp32 accumulator.
    hipMemsetAsync(hacc, 0, (size_t)N_NODES * 512 * 4, stream);
    edge_msg<<<N_EDGES / 4, 256, 0, stream>>>(hb, src, dst, score, denom, hacc);
    convert_h<<<((size_t)N_NODES * 512) / 256, 256, 0, stream>>>(
        hacc, flag, hb, d_out, layer == 1 ? 1 : 0);
  }
}

// Round 4
// 647.997 us; speedup vs baseline: 2.0922x; 2.0922x over previous
//
#include <hip/hip_runtime.h>
#include <hip/hip_bf16.h>
#include <stdint.h>

#define N_NODES 32768
#define N_EDGES 262144

typedef __attribute__((ext_vector_type(8))) short short8;
typedef __attribute__((ext_vector_type(4))) float f32x4;

__device__ __forceinline__ float bf2f(ushort u) {
  return __uint_as_float(((uint)u) << 16);
}
__device__ __forceinline__ ushort f2bf(float f) {
  uint x = __float_as_uint(f);
  uint r = (x + 0x7fffu + ((x >> 16) & 1u)) >> 16;
  return (ushort)r;
}
__device__ __forceinline__ float loadf(const void* p, size_t i, int isbf) {
  return isbf ? bf2f(((const ushort*)p)[i]) : ((const float*)p)[i];
}

// ---------------- dtype detection (bf16-packed vs fp32 inputs) ----------------
__global__ void detect_dtype(const uint* __restrict__ xw, int* __restrict__ flag) {
  __shared__ int cnt;
  if (threadIdx.x == 0) cnt = 0;
  __syncthreads();
  int good = 0;
  for (int i = threadIdx.x; i < 1024; i += 256) {
    uint lo = xw[i] & 0xFFFFu;
    uint ef = (lo >> 7) & 0xFFu;
    if (lo == 0u || (ef >= 0x60u && ef <= 0x90u)) good++;
  }
  atomicAdd(&cnt, good);
  __syncthreads();
  if (threadIdx.x == 0) *flag = (cnt >= 614) ? 1 : 0;
}

// ---------------- setup kernels ----------------
__global__ void setup_small(const void* __restrict__ ba, const void* __restrict__ bn,
                            const void* __restrict__ aw, const int* __restrict__ flag,
                            float* __restrict__ bias2, float* __restrict__ bnf,
                            float* __restrict__ wf) {
  int fl = *flag;
  int t = blockIdx.x * blockDim.x + threadIdx.x;
  if (t < 1024) bias2[t] = (t < 512) ? loadf(ba, t, fl) : 0.f;
  if (t < 512) { bnf[t] = loadf(bn, t, fl); wf[t] = loadf(aw, t, fl); }
}

__global__ void build_wnt(const void* __restrict__ Wn, const int* __restrict__ flag,
                          ushort* __restrict__ WnpT) {
  int fl = *flag;
  int t = blockIdx.x * blockDim.x + threadIdx.x;   // 512*128
  int n = t >> 7, k = t & 127;
  WnpT[t] = (k < 118) ? f2bf(loadf(Wn, (size_t)k * 512 + n, fl)) : (ushort)0;
}

__global__ void build_xp(const void* __restrict__ x, const int* __restrict__ flag,
                         ushort* __restrict__ xp) {
  int fl = *flag;
  int t = blockIdx.x * blockDim.x + threadIdx.x;   // 32768*128
  int i = t >> 7, k = t & 127;
  xp[t] = (k < 118) ? f2bf(loadf(x, (size_t)i * 118 + k, fl)) : (ushort)0;
}

// W2T[n][k] (1024 x 512): W2[k][j] = j<512 ? Wa[k][j] : Wa[512+k][j-512]
__global__ void build_w2t(const void* __restrict__ Wa, const int* __restrict__ flag,
                          ushort* __restrict__ W2T) {
  int fl = *flag;
  int t = blockIdx.x * blockDim.x + threadIdx.x;   // 1024*512
  int n = t >> 9, k = t & 511;
  size_t idx = (n < 512) ? ((size_t)k * 512 + n) : ((size_t)(512 + k) * 512 + (n - 512));
  W2T[t] = f2bf(loadf(Wa, idx, fl));
}

// ---------------- CSR build (dst-sorted edge index) ----------------
__global__ void csr_count(const int* __restrict__ dst, int* __restrict__ cnt) {
  int e = blockIdx.x * blockDim.x + threadIdx.x;
  atomicAdd(&cnt[dst[e]], 1);
}

// single block, 1024 threads, 32 elements each: exclusive scan of cnt -> rowptr & cursor
__global__ __launch_bounds__(1024)
void csr_scan(const int* __restrict__ cnt, int* __restrict__ rowptr,
              int* __restrict__ cursor) {
  __shared__ int part[1024];
  const int t = threadIdx.x;
  const int base = t * 32;
  int loc[32];
  int s = 0;
#pragma unroll
  for (int i = 0; i < 32; ++i) { loc[i] = s; s += cnt[base + i]; }
  part[t] = s;
  __syncthreads();
  for (int off = 1; off < 1024; off <<= 1) {
    int v = (t >= off) ? part[t - off] : 0;
    __syncthreads();
    part[t] += v;
    __syncthreads();
  }
  int pre = (t == 0) ? 0 : part[t - 1];
#pragma unroll
  for (int i = 0; i < 32; ++i) {
    int v = pre + loc[i];
    rowptr[base + i] = v;
    cursor[base + i] = v;
  }
  if (t == 1023) rowptr[N_NODES] = part[1023];
}

__global__ void csr_fill(const int* __restrict__ dst, int* __restrict__ cursor,
                         int* __restrict__ eidx) {
  int e = blockIdx.x * blockDim.x + threadIdx.x;
  int p = atomicAdd(&cursor[dst[e]], 1);
  eidx[p] = e;
}

// ---------------- GEMM: C[M,N](bf16) = A[M,K](bf16) @ B + bias; BT = B^T [N,K] ----------------
__global__ __launch_bounds__(256)
void gemm_bf16(const ushort* __restrict__ A, const ushort* __restrict__ BT,
               const float* __restrict__ bias, ushort* __restrict__ C,
               int M, int N, int K) {
  __shared__ __align__(16) ushort As[128 * 32];
  __shared__ __align__(16) ushort Bs[128 * 32];
  const int tid = threadIdx.x, wave = tid >> 6, lane = tid & 63;
  const int bm = blockIdx.y * 128, bn = blockIdx.x * 128;
  const int wm = (wave >> 1) * 64, wn = (wave & 1) * 64;
  const int fcol = lane & 15, quad = lane >> 4;

  const f32x4 zero = {0.f, 0.f, 0.f, 0.f};
  f32x4 acc[4][4];
#pragma unroll
  for (int i = 0; i < 4; ++i)
#pragma unroll
    for (int j = 0; j < 4; ++j) acc[i][j] = zero;

  for (int k0 = 0; k0 < K; k0 += 32) {
#pragma unroll
    for (int r = 0; r < 2; ++r) {
      int o = r * 4096 + wave * 1024 + lane * 16;
      int row = o >> 6;
      int ke = (o & 63) >> 1;
      short8 va = *(const short8*)(A + (size_t)(bm + row) * K + k0 + ke);
      short8 vb = *(const short8*)(BT + (size_t)(bn + row) * K + k0 + ke);
      *(short8*)&As[o >> 1] = va;
      *(short8*)&Bs[o >> 1] = vb;
    }
    __syncthreads();
    short8 a[4], b[4];
#pragma unroll
    for (int i = 0; i < 4; ++i) {
      a[i] = *(const short8*)&As[(wm + i * 16 + fcol) * 32 + quad * 8];
      b[i] = *(const short8*)&Bs[(wn + i * 16 + fcol) * 32 + quad * 8];
    }
#pragma unroll
    for (int i = 0; i < 4; ++i)
#pragma unroll
      for (int j = 0; j < 4; ++j)
        acc[i][j] = __builtin_amdgcn_mfma_f32_16x16x32_bf16(a[i], b[j], acc[i][j], 0, 0, 0);
    __syncthreads();
  }

#pragma unroll
  for (int i = 0; i < 4; ++i) {
    int rowb = bm + wm + i * 16 + quad * 4;
#pragma unroll
    for (int j = 0; j < 4; ++j) {
      int col = bn + wn + j * 16 + fcol;
      float bb = bias[col];
#pragma unroll
      for (int r = 0; r < 4; ++r) {
        C[(size_t)(rowb + r) * N + col] = f2bf(acc[i][j][r] + bb);
      }
    }
  }
}

// ---------------- edge pass: score only (no atomics) ----------------
__global__ __launch_bounds__(256)
void edge_score(const ushort* __restrict__ PQ, const int* __restrict__ src,
                const int* __restrict__ dst, const float* __restrict__ wf,
                float* __restrict__ score) {
  const int wave = threadIdx.x >> 6, lane = threadIdx.x & 63;
  const int e = blockIdx.x * 4 + wave;
  const int s = src[e], d = dst[e];
  const int c0 = lane * 8;
  const uint4 pu = *(const uint4*)(PQ + (size_t)s * 1024 + c0);
  const uint4 qu = *(const uint4*)(PQ + (size_t)d * 1024 + 512 + c0);
  const float4 w0 = *(const float4*)(wf + c0);
  const float4 w1 = *(const float4*)(wf + c0 + 4);
  const uint pw[4] = {pu.x, pu.y, pu.z, pu.w};
  const uint qw[4] = {qu.x, qu.y, qu.z, qu.w};
  const float wv[8] = {w0.x, w0.y, w0.z, w0.w, w1.x, w1.y, w1.z, w1.w};
  float part = 0.f;
#pragma unroll
  for (int w = 0; w < 4; ++w) {
    float pa = __uint_as_float(pw[w] << 16);
    float pb = __uint_as_float(pw[w] & 0xffff0000u);
    float qa = __uint_as_float(qw[w] << 16);
    float qb = __uint_as_float(qw[w] & 0xffff0000u);
    float ea = pa + qa; ea = (ea > 0.f) ? ea : 0.01f * ea;
    float eb = pb + qb; eb = (eb > 0.f) ? eb : 0.01f * eb;
    part += ea * wv[2 * w] + eb * wv[2 * w + 1];
  }
  part += __shfl_xor(part, 1);
  part += __shfl_xor(part, 2);
  part += __shfl_xor(part, 4);
  if ((lane & 7) == 0) score[(size_t)e * 8 + (lane >> 3)] = part;
}

// ---------------- node-centric fused softmax + aggregation ----------------
// one wave per dst node; lane covers channels lane*8..+7 (head = lane>>3)
__global__ __launch_bounds__(256)
void node_agg(const ushort* __restrict__ hb_in, const int* __restrict__ src,
              const int* __restrict__ eidx, const int* __restrict__ rowptr,
              const float* __restrict__ score, const int* __restrict__ flag,
              ushort* __restrict__ hb_out, void* __restrict__ out, int write_out) {
  const int wave = threadIdx.x >> 6, lane = threadIdx.x & 63;
  const int d = blockIdx.x * 4 + wave;
  const int beg = rowptr[d], end = rowptr[d + 1];

  // phase 1: per-head max & denom (lane h in 0..7 owns head h; all lanes mirror)
  const int h = lane & 7;
  float m = -3e38f;
  for (int j = beg; j < end; ++j)
    m = fmaxf(m, score[(size_t)eidx[j] * 8 + h]);
  float den = 0.f;
  for (int j = beg; j < end; ++j)
    den += __expf(score[(size_t)eidx[j] * 8 + h] - m);
  const float mh = __shfl(m, lane >> 3);
  const float dh = __shfl(den, lane >> 3);
  const float inv_dh = (end > beg) ? (1.f / dh) : 0.f;

  // phase 2: gather hb[src] rows, accumulate alpha-weighted sum
  float acc[8] = {0.f, 0.f, 0.f, 0.f, 0.f, 0.f, 0.f, 0.f};
  const int c0 = lane * 8;
  for (int j = beg; j < end; ++j) {
    const int e = eidx[j];
    const int s = src[e];
    const float alpha = __expf(score[(size_t)e * 8 + (lane >> 3)] - mh) * inv_dh;
    const uint4 hv = *(const uint4*)(hb_in + (size_t)s * 512 + c0);
    const uint w[4] = {hv.x, hv.y, hv.z, hv.w};
#pragma unroll
    for (int i = 0; i < 4; ++i) {
      acc[2 * i]     += __uint_as_float(w[i] << 16) * alpha;
      acc[2 * i + 1] += __uint_as_float(w[i] & 0xffff0000u) * alpha;
    }
  }

  // write node row once (bf16), plus final output
  uint o[4];
#pragma unroll
  for (int i = 0; i < 4; ++i)
    o[i] = (uint)f2bf(acc[2 * i]) | ((uint)f2bf(acc[2 * i + 1]) << 16);
  *(uint4*)(hb_out + (size_t)d * 512 + c0) = *(uint4*)o;
  if (write_out) {
    if (*flag) {
      *(uint4*)((ushort*)out + (size_t)d * 512 + c0) = *(uint4*)o;
    } else {
      float4 f0 = {acc[0], acc[1], acc[2], acc[3]};
      float4 f1 = {acc[4], acc[5], acc[6], acc[7]};
      *(float4*)((float*)out + (size_t)d * 512 + c0) = f0;
      *(float4*)((float*)out + (size_t)d * 512 + c0 + 4) = f1;
    }
  }
}

extern "C" void kernel_launch(void* const* d_in, const int* in_sizes, int n_in,
                              void* d_out, int out_size, void* d_ws, size_t ws_size,
                              hipStream_t stream) {
  const void* x   = d_in[0];
  const int*  src = (const int*)d_in[2];
  const int*  dst = (const int*)d_in[3];
  const void* Wn  = d_in[4];
  const void* bn  = d_in[5];
  const void* Wa  = d_in[8];
  const void* ba  = d_in[9];
  const void* aw  = d_in[10];

  char* ws = (char*)d_ws;
  size_t off = 0;
  auto alloc = [&](size_t bytes) {
    char* p = ws + off;
    off = (off + bytes + 255) & ~(size_t)255;
    return p;
  };
  ushort* hbA    = (ushort*)alloc((size_t)N_NODES * 512 * 2);   // 32 MB
  ushort* hbB    = (ushort*)alloc((size_t)N_NODES * 512 * 2);   // 32 MB
  ushort* PQ     = (ushort*)alloc((size_t)N_NODES * 1024 * 2);  // 64 MB
  float*  score  = (float*) alloc((size_t)N_EDGES * 8 * 4);     // 8 MB
  int*    eidx   = (int*)   alloc((size_t)N_EDGES * 4);         // 1 MB
  int*    rowptr = (int*)   alloc((size_t)(N_NODES + 1) * 4);
  int*    cnt    = (int*)   alloc((size_t)N_NODES * 4);
  int*    cursor = (int*)   alloc((size_t)N_NODES * 4);
  ushort* W2T    = (ushort*)alloc((size_t)1024 * 512 * 2);      // 1 MB
  float*  bias2  = (float*) alloc(1024 * 4);
  ushort* xp     = (ushort*)alloc((size_t)N_NODES * 128 * 2);   // 8 MB
  ushort* WnpT   = (ushort*)alloc((size_t)512 * 128 * 2);
  float*  bnf    = (float*) alloc(512 * 4);
  float*  wf     = (float*) alloc(512 * 4);
  int*    flag   = (int*)   alloc(256);

  detect_dtype<<<1, 256, 0, stream>>>((const uint*)x, flag);
  setup_small<<<4, 256, 0, stream>>>(ba, bn, aw, flag, bias2, bnf, wf);
  build_wnt<<<(512 * 128) / 256, 256, 0, stream>>>(Wn, flag, WnpT);
  build_xp<<<(N_NODES * 128) / 256, 256, 0, stream>>>(x, flag, xp);
  build_w2t<<<(1024 * 512) / 256, 256, 0, stream>>>(Wa, flag, W2T);

  // CSR over dst (index-only; rebuilt every launch since ws is re-poisoned)
  hipMemsetAsync(cnt, 0, (size_t)N_NODES * 4, stream);
  csr_count<<<N_EDGES / 256, 256, 0, stream>>>(dst, cnt);
  csr_scan<<<1, 1024, 0, stream>>>(cnt, rowptr, cursor);
  csr_fill<<<N_EDGES / 256, 256, 0, stream>>>(dst, cursor, eidx);

  // h0 = x @ Wn + bn   (K padded 118 -> 128)
  {
    dim3 g(512 / 128, N_NODES / 128);
    gemm_bf16<<<g, 256, 0, stream>>>(xp, WnpT, bnf, hbA, N_NODES, 512, 128);
  }

  ushort* hin = hbA;
  ushort* hout = hbB;
  for (int layer = 0; layer < 2; ++layer) {
    dim3 g(1024 / 128, N_NODES / 128);
    gemm_bf16<<<g, 256, 0, stream>>>(hin, W2T, bias2, PQ, N_NODES, 1024, 512);
    edge_score<<<N_EDGES / 4, 256, 0, stream>>>(PQ, src, dst, wf, score);
    node_agg<<<N_NODES / 4, 256, 0, stream>>>(hin, src, eidx, rowptr, score, flag,
                                              hout, d_out, layer == 1 ? 1 : 0);
    ushort* t = hin; hin = hout; hout = t;
  }
}

// Round 5
// 492.955 us; speedup vs baseline: 2.7502x; 1.3145x over previous
//
#include <hip/hip_runtime.h>
#include <hip/hip_bf16.h>
#include <stdint.h>

#define N_NODES 32768
#define N_EDGES 262144

typedef __attribute__((ext_vector_type(8))) short short8;
typedef __attribute__((ext_vector_type(4))) float f32x4;

__device__ __forceinline__ float bf2f(ushort u) {
  return __uint_as_float(((uint)u) << 16);
}
__device__ __forceinline__ ushort f2bf(float f) {
  uint x = __float_as_uint(f);
  uint r = (x + 0x7fffu + ((x >> 16) & 1u)) >> 16;
  return (ushort)r;
}
__device__ __forceinline__ float loadf(const void* p, size_t i, int isbf) {
  return isbf ? bf2f(((const ushort*)p)[i]) : ((const float*)p)[i];
}

// ---------------- dtype detection (bf16-packed vs fp32 inputs) ----------------
__global__ void detect_dtype(const uint* __restrict__ xw, int* __restrict__ flag) {
  __shared__ int cnt;
  if (threadIdx.x == 0) cnt = 0;
  __syncthreads();
  int good = 0;
  for (int i = threadIdx.x; i < 1024; i += 256) {
    uint lo = xw[i] & 0xFFFFu;
    uint ef = (lo >> 7) & 0xFFu;
    if (lo == 0u || (ef >= 0x60u && ef <= 0x90u)) good++;
  }
  atomicAdd(&cnt, good);
  __syncthreads();
  if (threadIdx.x == 0) *flag = (cnt >= 614) ? 1 : 0;
}

// ---------------- setup kernels ----------------
__global__ void setup_small(const void* __restrict__ ba, const void* __restrict__ bn,
                            const void* __restrict__ aw, const int* __restrict__ flag,
                            float* __restrict__ bias2, float* __restrict__ bnf,
                            float* __restrict__ wf) {
  int fl = *flag;
  int t = blockIdx.x * blockDim.x + threadIdx.x;
  if (t < 1024) bias2[t] = (t < 512) ? loadf(ba, t, fl) : 0.f;
  if (t < 512) { bnf[t] = loadf(bn, t, fl); wf[t] = loadf(aw, t, fl); }
}

__global__ void build_wnt(const void* __restrict__ Wn, const int* __restrict__ flag,
                          ushort* __restrict__ WnpT) {
  int fl = *flag;
  int t = blockIdx.x * blockDim.x + threadIdx.x;   // 512*128
  int n = t >> 7, k = t & 127;
  WnpT[t] = (k < 118) ? f2bf(loadf(Wn, (size_t)k * 512 + n, fl)) : (ushort)0;
}

__global__ void build_xp(const void* __restrict__ x, const int* __restrict__ flag,
                         ushort* __restrict__ xp) {
  int fl = *flag;
  int t = blockIdx.x * blockDim.x + threadIdx.x;   // 32768*128
  int i = t >> 7, k = t & 127;
  xp[t] = (k < 118) ? f2bf(loadf(x, (size_t)i * 118 + k, fl)) : (ushort)0;
}

// W2T[n][k] (1024 x 512): W2[k][j] = j<512 ? Wa[k][j] : Wa[512+k][j-512]
__global__ void build_w2t(const void* __restrict__ Wa, const int* __restrict__ flag,
                          ushort* __restrict__ W2T) {
  int fl = *flag;
  int t = blockIdx.x * blockDim.x + threadIdx.x;   // 1024*512
  int n = t >> 9, k = t & 511;
  size_t idx = (n < 512) ? ((size_t)k * 512 + n) : ((size_t)(512 + k) * 512 + (n - 512));
  W2T[t] = f2bf(loadf(Wa, idx, fl));
}

// ---------------- CSR build (dst-sorted edge index) ----------------
__global__ void csr_count(const int* __restrict__ dst, int* __restrict__ cnt) {
  int e = blockIdx.x * blockDim.x + threadIdx.x;
  atomicAdd(&cnt[dst[e]], 1);
}

__global__ __launch_bounds__(1024)
void csr_scan(const int* __restrict__ cnt, int* __restrict__ rowptr,
              int* __restrict__ cursor) {
  __shared__ int part[1024];
  const int t = threadIdx.x;
  const int base = t * 32;
  int loc[32];
  int s = 0;
#pragma unroll
  for (int i = 0; i < 32; ++i) { loc[i] = s; s += cnt[base + i]; }
  part[t] = s;
  __syncthreads();
  for (int off = 1; off < 1024; off <<= 1) {
    int v = (t >= off) ? part[t - off] : 0;
    __syncthreads();
    part[t] += v;
    __syncthreads();
  }
  int pre = (t == 0) ? 0 : part[t - 1];
#pragma unroll
  for (int i = 0; i < 32; ++i) {
    int v = pre + loc[i];
    rowptr[base + i] = v;
    cursor[base + i] = v;
  }
  if (t == 1023) rowptr[N_NODES] = part[1023];
}

__global__ void csr_fill(const int* __restrict__ dst, int* __restrict__ cursor,
                         int* __restrict__ eidx) {
  int e = blockIdx.x * blockDim.x + threadIdx.x;
  int p = atomicAdd(&cursor[dst[e]], 1);
  eidx[p] = e;
}

// ---------------- GEMM: C[M,N](bf16) = A[M,K](bf16) @ B + bias; BT = B^T [N,K] ----------------
__global__ __launch_bounds__(256)
void gemm_bf16(const ushort* __restrict__ A, const ushort* __restrict__ BT,
               const float* __restrict__ bias, ushort* __restrict__ C,
               int M, int N, int K) {
  __shared__ __align__(16) ushort As[128 * 32];
  __shared__ __align__(16) ushort Bs[128 * 32];
  const int tid = threadIdx.x, wave = tid >> 6, lane = tid & 63;
  const int bm = blockIdx.y * 128, bn = blockIdx.x * 128;
  const int wm = (wave >> 1) * 64, wn = (wave & 1) * 64;
  const int fcol = lane & 15, quad = lane >> 4;

  const f32x4 zero = {0.f, 0.f, 0.f, 0.f};
  f32x4 acc[4][4];
#pragma unroll
  for (int i = 0; i < 4; ++i)
#pragma unroll
    for (int j = 0; j < 4; ++j) acc[i][j] = zero;

  for (int k0 = 0; k0 < K; k0 += 32) {
#pragma unroll
    for (int r = 0; r < 2; ++r) {
      int o = r * 4096 + wave * 1024 + lane * 16;
      int row = o >> 6;
      int ke = (o & 63) >> 1;
      short8 va = *(const short8*)(A + (size_t)(bm + row) * K + k0 + ke);
      short8 vb = *(const short8*)(BT + (size_t)(bn + row) * K + k0 + ke);
      *(short8*)&As[o >> 1] = va;
      *(short8*)&Bs[o >> 1] = vb;
    }
    __syncthreads();
    short8 a[4], b[4];
#pragma unroll
    for (int i = 0; i < 4; ++i) {
      a[i] = *(const short8*)&As[(wm + i * 16 + fcol) * 32 + quad * 8];
      b[i] = *(const short8*)&Bs[(wn + i * 16 + fcol) * 32 + quad * 8];
    }
#pragma unroll
    for (int i = 0; i < 4; ++i)
#pragma unroll
      for (int j = 0; j < 4; ++j)
        acc[i][j] = __builtin_amdgcn_mfma_f32_16x16x32_bf16(a[i], b[j], acc[i][j], 0, 0, 0);
    __syncthreads();
  }

#pragma unroll
  for (int i = 0; i < 4; ++i) {
    int rowb = bm + wm + i * 16 + quad * 4;
#pragma unroll
    for (int j = 0; j < 4; ++j) {
      int col = bn + wn + j * 16 + fcol;
      float bb = bias[col];
#pragma unroll
      for (int r = 0; r < 4; ++r) {
        C[(size_t)(rowb + r) * N + col] = f2bf(acc[i][j][r] + bb);
      }
    }
  }
}

// ---------------- fused per-node: score + online-softmax + aggregation ----------------
// one wave per dst node; lane covers channels c0=lane*8..+7 (head = lane>>3, 64 ch/head)
__global__ __launch_bounds__(256)
void node_fused(const ushort* __restrict__ PQ, const ushort* __restrict__ hb_in,
                const int* __restrict__ src, const int* __restrict__ eidx,
                const int* __restrict__ rowptr, const float* __restrict__ wf,
                const int* __restrict__ flag, ushort* __restrict__ hb_out,
                void* __restrict__ out, int write_out) {
  const int wave = threadIdx.x >> 6, lane = threadIdx.x & 63;
  const int d = blockIdx.x * 4 + wave;
  const int beg = rowptr[d], end = rowptr[d + 1];
  const int c0 = lane * 8;

  // q_d row (dst half of PQ) and attn weights, held in registers for the node
  const uint4 qv = *(const uint4*)(PQ + (size_t)d * 1024 + 512 + c0);
  const uint qw[4] = {qv.x, qv.y, qv.z, qv.w};
  float q[8], w[8];
#pragma unroll
  for (int i = 0; i < 4; ++i) {
    q[2 * i]     = __uint_as_float(qw[i] << 16);
    q[2 * i + 1] = __uint_as_float(qw[i] & 0xffff0000u);
  }
  const float4 w0 = *(const float4*)(wf + c0);
  const float4 w1 = *(const float4*)(wf + c0 + 4);
  w[0] = w0.x; w[1] = w0.y; w[2] = w0.z; w[3] = w0.w;
  w[4] = w1.x; w[5] = w1.y; w[6] = w1.z; w[7] = w1.w;

  float m = -3e38f, den = 0.f;
  float acc[8] = {0.f, 0.f, 0.f, 0.f, 0.f, 0.f, 0.f, 0.f};

  int sj = (beg < end) ? src[eidx[beg]] : 0;   // pipelined src index
  for (int j = beg; j < end; ++j) {
    const int s = sj;
    if (j + 1 < end) sj = src[eidx[j + 1]];
    const uint4 pv = *(const uint4*)(PQ + (size_t)s * 1024 + c0);
    const uint4 hv = *(const uint4*)(hb_in + (size_t)s * 512 + c0);
    const uint pw[4] = {pv.x, pv.y, pv.z, pv.w};
    const uint hw[4] = {hv.x, hv.y, hv.z, hv.w};
    // per-lane partial score over its 8 channels
    float t = 0.f;
#pragma unroll
    for (int i = 0; i < 4; ++i) {
      float ea = __uint_as_float(pw[i] << 16) + q[2 * i];
      float eb = __uint_as_float(pw[i] & 0xffff0000u) + q[2 * i + 1];
      ea = (ea > 0.f) ? ea : 0.01f * ea;
      eb = (eb > 0.f) ? eb : 0.01f * eb;
      t += ea * w[2 * i] + eb * w[2 * i + 1];
    }
    // butterfly within the 8-lane head group -> every lane has its head's score
    t += __shfl_xor(t, 1);
    t += __shfl_xor(t, 2);
    t += __shfl_xor(t, 4);
    // online softmax update
    const float mnew = fmaxf(m, t);
    const float corr = __expf(m - mnew);   // exp(-inf)=0 on first edge
    const float ex = __expf(t - mnew);
    den = den * corr + ex;
#pragma unroll
    for (int i = 0; i < 4; ++i) {
      acc[2 * i]     = acc[2 * i] * corr     + ex * __uint_as_float(hw[i] << 16);
      acc[2 * i + 1] = acc[2 * i + 1] * corr + ex * __uint_as_float(hw[i] & 0xffff0000u);
    }
    m = mnew;
  }

  const float inv = (end > beg) ? (1.f / den) : 0.f;
  uint o[4];
#pragma unroll
  for (int i = 0; i < 4; ++i) {
    float v0 = acc[2 * i] * inv, v1 = acc[2 * i + 1] * inv;
    o[i] = (uint)f2bf(v0) | ((uint)f2bf(v1) << 16);
  }
  *(uint4*)(hb_out + (size_t)d * 512 + c0) = *(uint4*)o;
  if (write_out) {
    if (*flag) {
      *(uint4*)((ushort*)out + (size_t)d * 512 + c0) = *(uint4*)o;
    } else {
      float4 f0 = {acc[0] * inv, acc[1] * inv, acc[2] * inv, acc[3] * inv};
      float4 f1 = {acc[4] * inv, acc[5] * inv, acc[6] * inv, acc[7] * inv};
      *(float4*)((float*)out + (size_t)d * 512 + c0) = f0;
      *(float4*)((float*)out + (size_t)d * 512 + c0 + 4) = f1;
    }
  }
}

extern "C" void kernel_launch(void* const* d_in, const int* in_sizes, int n_in,
                              void* d_out, int out_size, void* d_ws, size_t ws_size,
                              hipStream_t stream) {
  const void* x   = d_in[0];
  const int*  src = (const int*)d_in[2];
  const int*  dst = (const int*)d_in[3];
  const void* Wn  = d_in[4];
  const void* bn  = d_in[5];
  const void* Wa  = d_in[8];
  const void* ba  = d_in[9];
  const void* aw  = d_in[10];

  char* ws = (char*)d_ws;
  size_t off = 0;
  auto alloc = [&](size_t bytes) {
    char* p = ws + off;
    off = (off + bytes + 255) & ~(size_t)255;
    return p;
  };
  ushort* hbA    = (ushort*)alloc((size_t)N_NODES * 512 * 2);   // 32 MB
  ushort* hbB    = (ushort*)alloc((size_t)N_NODES * 512 * 2);   // 32 MB
  ushort* PQ     = (ushort*)alloc((size_t)N_NODES * 1024 * 2);  // 64 MB
  int*    eidx   = (int*)   alloc((size_t)N_EDGES * 4);         // 1 MB
  int*    rowptr = (int*)   alloc((size_t)(N_NODES + 1) * 4);
  int*    cnt    = (int*)   alloc((size_t)N_NODES * 4);
  int*    cursor = (int*)   alloc((size_t)N_NODES * 4);
  ushort* W2T    = (ushort*)alloc((size_t)1024 * 512 * 2);      // 1 MB
  float*  bias2  = (float*) alloc(1024 * 4);
  ushort* xp     = (ushort*)alloc((size_t)N_NODES * 128 * 2);   // 8 MB
  ushort* WnpT   = (ushort*)alloc((size_t)512 * 128 * 2);
  float*  bnf    = (float*) alloc(512 * 4);
  float*  wf     = (float*) alloc(512 * 4);
  int*    flag   = (int*)   alloc(256);

  detect_dtype<<<1, 256, 0, stream>>>((const uint*)x, flag);
  setup_small<<<4, 256, 0, stream>>>(ba, bn, aw, flag, bias2, bnf, wf);
  build_wnt<<<(512 * 128) / 256, 256, 0, stream>>>(Wn, flag, WnpT);
  build_xp<<<(N_NODES * 128) / 256, 256, 0, stream>>>(x, flag, xp);
  build_w2t<<<(1024 * 512) / 256, 256, 0, stream>>>(Wa, flag, W2T);

  // CSR over dst (index-only; rebuilt every launch since ws is re-poisoned)
  hipMemsetAsync(cnt, 0, (size_t)N_NODES * 4, stream);
  csr_count<<<N_EDGES / 256, 256, 0, stream>>>(dst, cnt);
  csr_scan<<<1, 1024, 0, stream>>>(cnt, rowptr, cursor);
  csr_fill<<<N_EDGES / 256, 256, 0, stream>>>(dst, cursor, eidx);

  // h0 = x @ Wn + bn   (K padded 118 -> 128)
  {
    dim3 g(512 / 128, N_NODES / 128);
    gemm_bf16<<<g, 256, 0, stream>>>(xp, WnpT, bnf, hbA, N_NODES, 512, 128);
  }

  ushort* hin = hbA;
  ushort* hout = hbB;
  for (int layer = 0; layer < 2; ++layer) {
    dim3 g(1024 / 128, N_NODES / 128);
    gemm_bf16<<<g, 256, 0, stream>>>(hin, W2T, bias2, PQ, N_NODES, 1024, 512);
    node_fused<<<N_NODES / 4, 256, 0, stream>>>(PQ, hin, src, eidx, rowptr, wf, flag,
                                                hout, d_out, layer == 1 ? 1 : 0);
    ushort* t = hin; hin = hout; hout = t;
  }
}

// Round 6
// 485.972 us; speedup vs baseline: 2.7897x; 1.0144x over previous
//
#include <hip/hip_runtime.h>
#include <hip/hip_bf16.h>
#include <stdint.h>

#define N_NODES 32768
#define N_EDGES 262144

typedef __attribute__((ext_vector_type(8))) short short8;
typedef __attribute__((ext_vector_type(4))) float f32x4;

typedef const __attribute__((address_space(1))) void* gvp;
typedef __attribute__((address_space(3))) void* lvp;

__device__ __forceinline__ float bf2f(ushort u) {
  return __uint_as_float(((uint)u) << 16);
}
__device__ __forceinline__ ushort f2bf(float f) {
  uint x = __float_as_uint(f);
  uint r = (x + 0x7fffu + ((x >> 16) & 1u)) >> 16;
  return (ushort)r;
}
__device__ __forceinline__ float loadf(const void* p, size_t i, int isbf) {
  return isbf ? bf2f(((const ushort*)p)[i]) : ((const float*)p)[i];
}

// ---------------- dtype detection (bf16-packed vs fp32 inputs) ----------------
__global__ void detect_dtype(const uint* __restrict__ xw, int* __restrict__ flag) {
  __shared__ int cnt;
  if (threadIdx.x == 0) cnt = 0;
  __syncthreads();
  int good = 0;
  for (int i = threadIdx.x; i < 1024; i += 256) {
    uint lo = xw[i] & 0xFFFFu;
    uint ef = (lo >> 7) & 0xFFu;
    if (lo == 0u || (ef >= 0x60u && ef <= 0x90u)) good++;
  }
  atomicAdd(&cnt, good);
  __syncthreads();
  if (threadIdx.x == 0) *flag = (cnt >= 614) ? 1 : 0;
}

// ---------------- merged weight prep ----------------
// blocks [0,2048): W2T; [2048,2304): WnpT; [2304,2308): small vectors
__global__ void prep_weights(const void* __restrict__ Wa, const void* __restrict__ Wn,
                             const void* __restrict__ ba, const void* __restrict__ bn,
                             const void* __restrict__ aw, const int* __restrict__ flag,
                             ushort* __restrict__ W2T, ushort* __restrict__ WnpT,
                             float* __restrict__ bias2, float* __restrict__ bnf,
                             float* __restrict__ wf) {
  const int fl = *flag;
  const int b = blockIdx.x;
  if (b < 2048) {
    int t = b * 256 + threadIdx.x;           // 1024*512
    int n = t >> 9, k = t & 511;
    size_t idx = (n < 512) ? ((size_t)k * 512 + n) : ((size_t)(512 + k) * 512 + (n - 512));
    W2T[t] = f2bf(loadf(Wa, idx, fl));
  } else if (b < 2304) {
    int t = (b - 2048) * 256 + threadIdx.x;  // 512*128
    int n = t >> 7, k = t & 127;
    WnpT[t] = (k < 118) ? f2bf(loadf(Wn, (size_t)k * 512 + n, fl)) : (ushort)0;
  } else {
    int t = (b - 2304) * 256 + threadIdx.x;  // 1024
    if (t < 1024) bias2[t] = (t < 512) ? loadf(ba, t, fl) : 0.f;
    if (t < 512) { bnf[t] = loadf(bn, t, fl); wf[t] = loadf(aw, t, fl); }
  }
}

__global__ void build_xp(const void* __restrict__ x, const int* __restrict__ flag,
                         ushort* __restrict__ xp) {
  int fl = *flag;
  int t = blockIdx.x * blockDim.x + threadIdx.x;   // 32768*128
  int i = t >> 7, k = t & 127;
  xp[t] = (k < 118) ? f2bf(loadf(x, (size_t)i * 118 + k, fl)) : (ushort)0;
}

// ---------------- CSR build (dst-sorted edge index) ----------------
__global__ void csr_count(const int* __restrict__ dst, int* __restrict__ cnt) {
  int e = blockIdx.x * blockDim.x + threadIdx.x;
  atomicAdd(&cnt[dst[e]], 1);
}

__global__ __launch_bounds__(1024)
void csr_scan(const int* __restrict__ cnt, int* __restrict__ rowptr,
              int* __restrict__ cursor) {
  __shared__ int part[1024];
  const int t = threadIdx.x;
  const int base = t * 32;
  int loc[32];
  int s = 0;
#pragma unroll
  for (int i = 0; i < 32; ++i) { loc[i] = s; s += cnt[base + i]; }
  part[t] = s;
  __syncthreads();
  for (int off = 1; off < 1024; off <<= 1) {
    int v = (t >= off) ? part[t - off] : 0;
    __syncthreads();
    part[t] += v;
    __syncthreads();
  }
  int pre = (t == 0) ? 0 : part[t - 1];
#pragma unroll
  for (int i = 0; i < 32; ++i) {
    int v = pre + loc[i];
    rowptr[base + i] = v;
    cursor[base + i] = v;
  }
  if (t == 1023) rowptr[N_NODES] = part[1023];
}

__global__ void csr_fill(const int* __restrict__ dst, int* __restrict__ cursor,
                         int* __restrict__ eidx) {
  int e = blockIdx.x * blockDim.x + threadIdx.x;
  int p = atomicAdd(&cursor[dst[e]], 1);
  eidx[p] = e;
}

// ---------------- GEMM: C[M,N](bf16) = A[M,K](bf16) @ B + bias; BT = B^T [N,K] ----------------
// 128x128 tile, 4 waves, BK=32, 16x16x32 MFMA, global_load_lds width-16 staging (m97).
__global__ __launch_bounds__(256)
void gemm_bf16(const ushort* __restrict__ A, const ushort* __restrict__ BT,
               const float* __restrict__ bias, ushort* __restrict__ C,
               int M, int N, int K) {
  __shared__ __align__(16) ushort As[128 * 32];
  __shared__ __align__(16) ushort Bs[128 * 32];
  const int tid = threadIdx.x, wave = tid >> 6, lane = tid & 63;
  const int bm = blockIdx.y * 128, bn = blockIdx.x * 128;
  const int wm = (wave >> 1) * 64, wn = (wave & 1) * 64;
  const int fcol = lane & 15, quad = lane >> 4;

  const f32x4 zero = {0.f, 0.f, 0.f, 0.f};
  f32x4 acc[4][4];
#pragma unroll
  for (int i = 0; i < 4; ++i)
#pragma unroll
    for (int j = 0; j < 4; ++j) acc[i][j] = zero;

  for (int k0 = 0; k0 < K; k0 += 32) {
    // async global->LDS staging: LDS dest = wave-uniform base + lane*16 B
#pragma unroll
    for (int r = 0; r < 2; ++r) {
      int o = r * 4096 + wave * 1024 + lane * 16;   // byte offset in 128x32 tile
      int row = o >> 6;                              // 64 B per tile row
      int ke = (o & 63) >> 1;
      const ushort* gA = A + (size_t)(bm + row) * K + k0 + ke;
      const ushort* gB = BT + (size_t)(bn + row) * K + k0 + ke;
      ushort* lA = As + ((r * 4096 + wave * 1024) >> 1);  // wave-uniform
      ushort* lB = Bs + ((r * 4096 + wave * 1024) >> 1);
      __builtin_amdgcn_global_load_lds((gvp)(const void*)gA, (lvp)(void*)lA, 16, 0, 0);
      __builtin_amdgcn_global_load_lds((gvp)(const void*)gB, (lvp)(void*)lB, 16, 0, 0);
    }
    __syncthreads();
    short8 a[4], b[4];
#pragma unroll
    for (int i = 0; i < 4; ++i) {
      a[i] = *(const short8*)&As[(wm + i * 16 + fcol) * 32 + quad * 8];
      b[i] = *(const short8*)&Bs[(wn + i * 16 + fcol) * 32 + quad * 8];
    }
#pragma unroll
    for (int i = 0; i < 4; ++i)
#pragma unroll
      for (int j = 0; j < 4; ++j)
        acc[i][j] = __builtin_amdgcn_mfma_f32_16x16x32_bf16(a[i], b[j], acc[i][j], 0, 0, 0);
    __syncthreads();
  }

#pragma unroll
  for (int i = 0; i < 4; ++i) {
    int rowb = bm + wm + i * 16 + quad * 4;
#pragma unroll
    for (int j = 0; j < 4; ++j) {
      int col = bn + wn + j * 16 + fcol;
      float bb = bias[col];
#pragma unroll
      for (int r = 0; r < 4; ++r) {
        C[(size_t)(rowb + r) * N + col] = f2bf(acc[i][j][r] + bb);
      }
    }
  }
}

// ---------------- fused per-node: score + online-softmax + aggregation ----------------
__global__ __launch_bounds__(256)
void node_fused(const ushort* __restrict__ PQ, const ushort* __restrict__ hb_in,
                const int* __restrict__ src, const int* __restrict__ eidx,
                const int* __restrict__ rowptr, const float* __restrict__ wf,
                const int* __restrict__ flag, ushort* __restrict__ hb_out,
                void* __restrict__ out, int write_out) {
  const int wave = threadIdx.x >> 6, lane = threadIdx.x & 63;
  const int d = blockIdx.x * 4 + wave;
  const int beg = rowptr[d], end = rowptr[d + 1];
  const int c0 = lane * 8;

  const uint4 qv = *(const uint4*)(PQ + (size_t)d * 1024 + 512 + c0);
  const uint qw[4] = {qv.x, qv.y, qv.z, qv.w};
  float q[8], w[8];
#pragma unroll
  for (int i = 0; i < 4; ++i) {
    q[2 * i]     = __uint_as_float(qw[i] << 16);
    q[2 * i + 1] = __uint_as_float(qw[i] & 0xffff0000u);
  }
  const float4 w0 = *(const float4*)(wf + c0);
  const float4 w1 = *(const float4*)(wf + c0 + 4);
  w[0] = w0.x; w[1] = w0.y; w[2] = w0.z; w[3] = w0.w;
  w[4] = w1.x; w[5] = w1.y; w[6] = w1.z; w[7] = w1.w;

  float m = -3e38f, den = 0.f;
  float acc[8] = {0.f, 0.f, 0.f, 0.f, 0.f, 0.f, 0.f, 0.f};

  int sj = (beg < end) ? src[eidx[beg]] : 0;
  for (int j = beg; j < end; ++j) {
    const int s = sj;
    if (j + 1 < end) sj = src[eidx[j + 1]];
    const uint4 pv = *(const uint4*)(PQ + (size_t)s * 1024 + c0);
    const uint4 hv = *(const uint4*)(hb_in + (size_t)s * 512 + c0);
    const uint pw[4] = {pv.x, pv.y, pv.z, pv.w};
    const uint hw[4] = {hv.x, hv.y, hv.z, hv.w};
    float t = 0.f;
#pragma unroll
    for (int i = 0; i < 4; ++i) {
      float ea = __uint_as_float(pw[i] << 16) + q[2 * i];
      float eb = __uint_as_float(pw[i] & 0xffff0000u) + q[2 * i + 1];
      ea = (ea > 0.f) ? ea : 0.01f * ea;
      eb = (eb > 0.f) ? eb : 0.01f * eb;
      t += ea * w[2 * i] + eb * w[2 * i + 1];
    }
    t += __shfl_xor(t, 1);
    t += __shfl_xor(t, 2);
    t += __shfl_xor(t, 4);
    const float mnew = fmaxf(m, t);
    const float corr = __expf(m - mnew);
    const float ex = __expf(t - mnew);
    den = den * corr + ex;
#pragma unroll
    for (int i = 0; i < 4; ++i) {
      acc[2 * i]     = acc[2 * i] * corr     + ex * __uint_as_float(hw[i] << 16);
      acc[2 * i + 1] = acc[2 * i + 1] * corr + ex * __uint_as_float(hw[i] & 0xffff0000u);
    }
    m = mnew;
  }

  const float inv = (end > beg) ? (1.f / den) : 0.f;
  uint o[4];
#pragma unroll
  for (int i = 0; i < 4; ++i) {
    float v0 = acc[2 * i] * inv, v1 = acc[2 * i + 1] * inv;
    o[i] = (uint)f2bf(v0) | ((uint)f2bf(v1) << 16);
  }
  *(uint4*)(hb_out + (size_t)d * 512 + c0) = *(uint4*)o;
  if (write_out) {
    if (*flag) {
      *(uint4*)((ushort*)out + (size_t)d * 512 + c0) = *(uint4*)o;
    } else {
      float4 f0 = {acc[0] * inv, acc[1] * inv, acc[2] * inv, acc[3] * inv};
      float4 f1 = {acc[4] * inv, acc[5] * inv, acc[6] * inv, acc[7] * inv};
      *(float4*)((float*)out + (size_t)d * 512 + c0) = f0;
      *(float4*)((float*)out + (size_t)d * 512 + c0 + 4) = f1;
    }
  }
}

extern "C" void kernel_launch(void* const* d_in, const int* in_sizes, int n_in,
                              void* d_out, int out_size, void* d_ws, size_t ws_size,
                              hipStream_t stream) {
  const void* x   = d_in[0];
  const int*  src = (const int*)d_in[2];
  const int*  dst = (const int*)d_in[3];
  const void* Wn  = d_in[4];
  const void* bn  = d_in[5];
  const void* Wa  = d_in[8];
  const void* ba  = d_in[9];
  const void* aw  = d_in[10];

  char* ws = (char*)d_ws;
  size_t off = 0;
  auto alloc = [&](size_t bytes) {
    char* p = ws + off;
    off = (off + bytes + 255) & ~(size_t)255;
    return p;
  };
  ushort* hbA    = (ushort*)alloc((size_t)N_NODES * 512 * 2);   // 32 MB
  ushort* hbB    = (ushort*)alloc((size_t)N_NODES * 512 * 2);   // 32 MB
  ushort* PQ     = (ushort*)alloc((size_t)N_NODES * 1024 * 2);  // 64 MB
  int*    eidx   = (int*)   alloc((size_t)N_EDGES * 4);         // 1 MB
  int*    rowptr = (int*)   alloc((size_t)(N_NODES + 1) * 4);
  int*    cnt    = (int*)   alloc((size_t)N_NODES * 4);
  int*    cursor = (int*)   alloc((size_t)N_NODES * 4);
  ushort* W2T    = (ushort*)alloc((size_t)1024 * 512 * 2);      // 1 MB
  float*  bias2  = (float*) alloc(1024 * 4);
  ushort* xp     = (ushort*)alloc((size_t)N_NODES * 128 * 2);   // 8 MB
  ushort* WnpT   = (ushort*)alloc((size_t)512 * 128 * 2);
  float*  bnf    = (float*) alloc(512 * 4);
  float*  wf     = (float*) alloc(512 * 4);
  int*    flag   = (int*)   alloc(256);

  detect_dtype<<<1, 256, 0, stream>>>((const uint*)x, flag);
  prep_weights<<<2308, 256, 0, stream>>>(Wa, Wn, ba, bn, aw, flag,
                                         W2T, WnpT, bias2, bnf, wf);
  build_xp<<<(N_NODES * 128) / 256, 256, 0, stream>>>(x, flag, xp);

  // CSR over dst (index-only; rebuilt every launch since ws is re-poisoned)
  hipMemsetAsync(cnt, 0, (size_t)N_NODES * 4, stream);
  csr_count<<<N_EDGES / 256, 256, 0, stream>>>(dst, cnt);
  csr_scan<<<1, 1024, 0, stream>>>(cnt, rowptr, cursor);
  csr_fill<<<N_EDGES / 256, 256, 0, stream>>>(dst, cursor, eidx);

  // h0 = x @ Wn + bn   (K padded 118 -> 128)
  {
    dim3 g(512 / 128, N_NODES / 128);
    gemm_bf16<<<g, 256, 0, stream>>>(xp, WnpT, bnf, hbA, N_NODES, 512, 128);
  }

  ushort* hin = hbA;
  ushort* hout = hbB;
  for (int layer = 0; layer < 2; ++layer) {
    dim3 g(1024 / 128, N_NODES / 128);
    gemm_bf16<<<g, 256, 0, stream>>>(hin, W2T, bias2, PQ, N_NODES, 1024, 512);
    node_fused<<<N_NODES / 4, 256, 0, stream>>>(PQ, hin, src, eidx, rowptr, wf, flag,
                                                hout, d_out, layer == 1 ? 1 : 0);
    ushort* t = hin; hin = hout; hout = t;
  }
}

// Round 7
// 460.809 us; speedup vs baseline: 2.9420x; 1.0546x over previous
//
#include <hip/hip_runtime.h>
#include <hip/hip_bf16.h>
#include <stdint.h>

#define N_NODES 32768
#define N_EDGES 262144

typedef __attribute__((ext_vector_type(8))) short short8;
typedef __attribute__((ext_vector_type(4))) float f32x4;

typedef const __attribute__((address_space(1))) void* gvp;
typedef __attribute__((address_space(3))) void* lvp;

__device__ __forceinline__ float bf2f(ushort u) {
  return __uint_as_float(((uint)u) << 16);
}
__device__ __forceinline__ ushort f2bf(float f) {
  uint x = __float_as_uint(f);
  uint r = (x + 0x7fffu + ((x >> 16) & 1u)) >> 16;
  return (ushort)r;
}
__device__ __forceinline__ float loadf(const void* p, size_t i, int isbf) {
  return isbf ? bf2f(((const ushort*)p)[i]) : ((const float*)p)[i];
}

// ---------------- dtype detection (bf16-packed vs fp32 inputs) ----------------
__global__ void detect_dtype(const uint* __restrict__ xw, int* __restrict__ flag) {
  __shared__ int cnt;
  if (threadIdx.x == 0) cnt = 0;
  __syncthreads();
  int good = 0;
  for (int i = threadIdx.x; i < 1024; i += 256) {
    uint lo = xw[i] & 0xFFFFu;
    uint ef = (lo >> 7) & 0xFFu;
    if (lo == 0u || (ef >= 0x60u && ef <= 0x90u)) good++;
  }
  atomicAdd(&cnt, good);
  __syncthreads();
  if (threadIdx.x == 0) *flag = (cnt >= 614) ? 1 : 0;
}

// ---------------- merged prep: all weights + xp ----------------
// blocks [0,2048): W2T (1024x512)       [2048,2304): WnpT (512x128)
// [2304,2560): Wn_pad (128x512)         [2560,2564): small vectors
// [2564,...): xp (32768x128)
__global__ void prep_all(const void* __restrict__ Wa, const void* __restrict__ Wn,
                         const void* __restrict__ ba, const void* __restrict__ bn,
                         const void* __restrict__ aw, const void* __restrict__ x,
                         const int* __restrict__ flag,
                         ushort* __restrict__ W2T, ushort* __restrict__ WnpT,
                         ushort* __restrict__ Wn_pad, float* __restrict__ bias2,
                         float* __restrict__ bnf, float* __restrict__ wf,
                         float* __restrict__ zbias, ushort* __restrict__ xp) {
  const int fl = *flag;
  const int b = blockIdx.x;
  if (b < 2048) {
    int t = b * 256 + threadIdx.x;           // 1024*512
    int n = t >> 9, k = t & 511;
    size_t idx = (n < 512) ? ((size_t)k * 512 + n) : ((size_t)(512 + k) * 512 + (n - 512));
    W2T[t] = f2bf(loadf(Wa, idx, fl));
  } else if (b < 2304) {
    int t = (b - 2048) * 256 + threadIdx.x;  // 512*128: WnpT[n][k] = Wn[k][n]
    int n = t >> 7, k = t & 127;
    WnpT[t] = (k < 118) ? f2bf(loadf(Wn, (size_t)k * 512 + n, fl)) : (ushort)0;
  } else if (b < 2560) {
    int t = (b - 2304) * 256 + threadIdx.x;  // 128*512: Wn_pad[n][j] = Wn[n][j] (rows padded)
    int n = t >> 9, j = t & 511;
    Wn_pad[t] = (n < 118) ? f2bf(loadf(Wn, (size_t)n * 512 + j, fl)) : (ushort)0;
  } else if (b < 2564) {
    int t = (b - 2560) * 256 + threadIdx.x;  // 1024
    if (t < 1024) bias2[t] = (t < 512) ? loadf(ba, t, fl) : 0.f;
    if (t < 512) { bnf[t] = loadf(bn, t, fl); wf[t] = loadf(aw, t, fl); }
    if (t < 128) zbias[t] = 0.f;
  } else {
    int t = (b - 2564) * 256 + threadIdx.x;  // 32768*128
    int i = t >> 7, k = t & 127;
    xp[t] = (k < 118) ? f2bf(loadf(x, (size_t)i * 118 + k, fl)) : (ushort)0;
  }
}

// bc[j] = sum_k bnf[k] * W2[k][j] + bias2[j]   (W2T is [1024][512])
// one wave per output j
__global__ __launch_bounds__(256)
void build_bc(const ushort* __restrict__ W2T, const float* __restrict__ bnf,
              const float* __restrict__ bias2, float* __restrict__ bc) {
  const int wave = threadIdx.x >> 6, lane = threadIdx.x & 63;
  const int j = blockIdx.x * 4 + wave;   // 256 blocks -> 1024 outputs
  const uint4 v = *(const uint4*)(W2T + (size_t)j * 512 + lane * 8);
  const float4 b0 = *(const float4*)(bnf + lane * 8);
  const float4 b1 = *(const float4*)(bnf + lane * 8 + 4);
  const uint w[4] = {v.x, v.y, v.z, v.w};
  const float bb[8] = {b0.x, b0.y, b0.z, b0.w, b1.x, b1.y, b1.z, b1.w};
  float s = 0.f;
#pragma unroll
  for (int i = 0; i < 4; ++i) {
    s += __uint_as_float(w[i] << 16) * bb[2 * i];
    s += __uint_as_float(w[i] & 0xffff0000u) * bb[2 * i + 1];
  }
  s += __shfl_xor(s, 1);  s += __shfl_xor(s, 2);  s += __shfl_xor(s, 4);
  s += __shfl_xor(s, 8);  s += __shfl_xor(s, 16); s += __shfl_xor(s, 32);
  if (lane == 0) bc[j] = s + bias2[j];
}

// ---------------- CSR build (dst-sorted edge index) ----------------
__global__ void csr_count(const int* __restrict__ dst, int* __restrict__ cnt) {
  int e = blockIdx.x * blockDim.x + threadIdx.x;
  atomicAdd(&cnt[dst[e]], 1);
}

__global__ __launch_bounds__(1024)
void csr_scan(const int* __restrict__ cnt, int* __restrict__ rowptr,
              int* __restrict__ cursor) {
  __shared__ int part[1024];
  const int t = threadIdx.x;
  const int base = t * 32;
  int loc[32];
  int s = 0;
#pragma unroll
  for (int i = 0; i < 32; ++i) { loc[i] = s; s += cnt[base + i]; }
  part[t] = s;
  __syncthreads();
  for (int off = 1; off < 1024; off <<= 1) {
    int v = (t >= off) ? part[t - off] : 0;
    __syncthreads();
    part[t] += v;
    __syncthreads();
  }
  int pre = (t == 0) ? 0 : part[t - 1];
#pragma unroll
  for (int i = 0; i < 32; ++i) {
    int v = pre + loc[i];
    rowptr[base + i] = v;
    cursor[base + i] = v;
  }
  if (t == 1023) rowptr[N_NODES] = part[1023];
}

__global__ void csr_fill(const int* __restrict__ dst, int* __restrict__ cursor,
                         int* __restrict__ eidx) {
  int e = blockIdx.x * blockDim.x + threadIdx.x;
  int p = atomicAdd(&cursor[dst[e]], 1);
  eidx[p] = e;
}

// ---------------- GEMM: C[M,N](bf16) = A[M,K](bf16) @ B + bias; BT = B^T [N,K] ----------------
__global__ __launch_bounds__(256)
void gemm_bf16(const ushort* __restrict__ A, const ushort* __restrict__ BT,
               const float* __restrict__ bias, ushort* __restrict__ C,
               int M, int N, int K) {
  __shared__ __align__(16) ushort As[128 * 32];
  __shared__ __align__(16) ushort Bs[128 * 32];
  const int tid = threadIdx.x, wave = tid >> 6, lane = tid & 63;
  const int bm = blockIdx.y * 128, bn = blockIdx.x * 128;
  const int wm = (wave >> 1) * 64, wn = (wave & 1) * 64;
  const int fcol = lane & 15, quad = lane >> 4;

  const f32x4 zero = {0.f, 0.f, 0.f, 0.f};
  f32x4 acc[4][4];
#pragma unroll
  for (int i = 0; i < 4; ++i)
#pragma unroll
    for (int j = 0; j < 4; ++j) acc[i][j] = zero;

  for (int k0 = 0; k0 < K; k0 += 32) {
#pragma unroll
    for (int r = 0; r < 2; ++r) {
      int o = r * 4096 + wave * 1024 + lane * 16;
      int row = o >> 6;
      int ke = (o & 63) >> 1;
      const ushort* gA = A + (size_t)(bm + row) * K + k0 + ke;
      const ushort* gB = BT + (size_t)(bn + row) * K + k0 + ke;
      ushort* lA = As + ((r * 4096 + wave * 1024) >> 1);
      ushort* lB = Bs + ((r * 4096 + wave * 1024) >> 1);
      __builtin_amdgcn_global_load_lds((gvp)(const void*)gA, (lvp)(void*)lA, 16, 0, 0);
      __builtin_amdgcn_global_load_lds((gvp)(const void*)gB, (lvp)(void*)lB, 16, 0, 0);
    }
    __syncthreads();
    short8 a[4], b[4];
#pragma unroll
    for (int i = 0; i < 4; ++i) {
      a[i] = *(const short8*)&As[(wm + i * 16 + fcol) * 32 + quad * 8];
      b[i] = *(const short8*)&Bs[(wn + i * 16 + fcol) * 32 + quad * 8];
    }
#pragma unroll
    for (int i = 0; i < 4; ++i)
#pragma unroll
      for (int j = 0; j < 4; ++j)
        acc[i][j] = __builtin_amdgcn_mfma_f32_16x16x32_bf16(a[i], b[j], acc[i][j], 0, 0, 0);
    __syncthreads();
  }

#pragma unroll
  for (int i = 0; i < 4; ++i) {
    int rowb = bm + wm + i * 16 + quad * 4;
#pragma unroll
    for (int j = 0; j < 4; ++j) {
      int col = bn + wn + j * 16 + fcol;
      float bb = bias[col];
#pragma unroll
      for (int r = 0; r < 4; ++r) {
        C[(size_t)(rowb + r) * N + col] = f2bf(acc[i][j][r] + bb);
      }
    }
  }
}

// ---------------- fused per-node: score + online-softmax + aggregation ----------------
__global__ __launch_bounds__(256)
void node_fused(const ushort* __restrict__ PQ, const ushort* __restrict__ hb_in,
                const int* __restrict__ src, const int* __restrict__ eidx,
                const int* __restrict__ rowptr, const float* __restrict__ wf,
                const int* __restrict__ flag, ushort* __restrict__ hb_out,
                void* __restrict__ out, int write_out) {
  const int wave = threadIdx.x >> 6, lane = threadIdx.x & 63;
  const int d = blockIdx.x * 4 + wave;
  const int beg = rowptr[d], end = rowptr[d + 1];
  const int c0 = lane * 8;

  const uint4 qv = *(const uint4*)(PQ + (size_t)d * 1024 + 512 + c0);
  const uint qw[4] = {qv.x, qv.y, qv.z, qv.w};
  float q[8], w[8];
#pragma unroll
  for (int i = 0; i < 4; ++i) {
    q[2 * i]     = __uint_as_float(qw[i] << 16);
    q[2 * i + 1] = __uint_as_float(qw[i] & 0xffff0000u);
  }
  const float4 w0 = *(const float4*)(wf + c0);
  const float4 w1 = *(const float4*)(wf + c0 + 4);
  w[0] = w0.x; w[1] = w0.y; w[2] = w0.z; w[3] = w0.w;
  w[4] = w1.x; w[5] = w1.y; w[6] = w1.z; w[7] = w1.w;

  float m = -3e38f, den = 0.f;
  float acc[8] = {0.f, 0.f, 0.f, 0.f, 0.f, 0.f, 0.f, 0.f};

  int sj = (beg < end) ? src[eidx[beg]] : 0;
  for (int j = beg; j < end; ++j) {
    const int s = sj;
    if (j + 1 < end) sj = src[eidx[j + 1]];
    const uint4 pv = *(const uint4*)(PQ + (size_t)s * 1024 + c0);
    const uint4 hv = *(const uint4*)(hb_in + (size_t)s * 512 + c0);
    const uint pw[4] = {pv.x, pv.y, pv.z, pv.w};
    const uint hw[4] = {hv.x, hv.y, hv.z, hv.w};
    float t = 0.f;
#pragma unroll
    for (int i = 0; i < 4; ++i) {
      float ea = __uint_as_float(pw[i] << 16) + q[2 * i];
      float eb = __uint_as_float(pw[i] & 0xffff0000u) + q[2 * i + 1];
      ea = (ea > 0.f) ? ea : 0.01f * ea;
      eb = (eb > 0.f) ? eb : 0.01f * eb;
      t += ea * w[2 * i] + eb * w[2 * i + 1];
    }
    t += __shfl_xor(t, 1);
    t += __shfl_xor(t, 2);
    t += __shfl_xor(t, 4);
    // online softmax; rescale path only when some head's max moves (wave-uniform)
    if (__any(t > m)) {
      const float mnew = fmaxf(m, t);
      const float corr = __expf(m - mnew);
      const float ex = __expf(t - mnew);
      den = den * corr + ex;
#pragma unroll
      for (int i = 0; i < 4; ++i) {
        acc[2 * i]     = acc[2 * i] * corr     + ex * __uint_as_float(hw[i] << 16);
        acc[2 * i + 1] = acc[2 * i + 1] * corr + ex * __uint_as_float(hw[i] & 0xffff0000u);
      }
      m = mnew;
    } else {
      const float ex = __expf(t - m);
      den += ex;
#pragma unroll
      for (int i = 0; i < 4; ++i) {
        acc[2 * i]     += ex * __uint_as_float(hw[i] << 16);
        acc[2 * i + 1] += ex * __uint_as_float(hw[i] & 0xffff0000u);
      }
    }
  }

  const float inv = (end > beg) ? (1.f / den) : 0.f;
  uint o[4];
#pragma unroll
  for (int i = 0; i < 4; ++i) {
    float v0 = acc[2 * i] * inv, v1 = acc[2 * i + 1] * inv;
    o[i] = (uint)f2bf(v0) | ((uint)f2bf(v1) << 16);
  }
  *(uint4*)(hb_out + (size_t)d * 512 + c0) = *(uint4*)o;
  if (write_out) {
    if (*flag) {
      *(uint4*)((ushort*)out + (size_t)d * 512 + c0) = *(uint4*)o;
    } else {
      float4 f0 = {acc[0] * inv, acc[1] * inv, acc[2] * inv, acc[3] * inv};
      float4 f1 = {acc[4] * inv, acc[5] * inv, acc[6] * inv, acc[7] * inv};
      *(float4*)((float*)out + (size_t)d * 512 + c0) = f0;
      *(float4*)((float*)out + (size_t)d * 512 + c0 + 4) = f1;
    }
  }
}

extern "C" void kernel_launch(void* const* d_in, const int* in_sizes, int n_in,
                              void* d_out, int out_size, void* d_ws, size_t ws_size,
                              hipStream_t stream) {
  const void* x   = d_in[0];
  const int*  src = (const int*)d_in[2];
  const int*  dst = (const int*)d_in[3];
  const void* Wn  = d_in[4];
  const void* bn  = d_in[5];
  const void* Wa  = d_in[8];
  const void* ba  = d_in[9];
  const void* aw  = d_in[10];

  char* ws = (char*)d_ws;
  size_t off = 0;
  auto alloc = [&](size_t bytes) {
    char* p = ws + off;
    off = (off + bytes + 255) & ~(size_t)255;
    return p;
  };
  ushort* hbA    = (ushort*)alloc((size_t)N_NODES * 512 * 2);   // 32 MB
  ushort* hbB    = (ushort*)alloc((size_t)N_NODES * 512 * 2);   // 32 MB
  ushort* PQ     = (ushort*)alloc((size_t)N_NODES * 1024 * 2);  // 64 MB
  int*    eidx   = (int*)   alloc((size_t)N_EDGES * 4);         // 1 MB
  int*    rowptr = (int*)   alloc((size_t)(N_NODES + 1) * 4);
  int*    cnt    = (int*)   alloc((size_t)N_NODES * 4);
  int*    cursor = (int*)   alloc((size_t)N_NODES * 4);
  ushort* W2T    = (ushort*)alloc((size_t)1024 * 512 * 2);      // 1 MB
  ushort* WcT    = (ushort*)alloc((size_t)1024 * 128 * 2);      // 256 KB
  ushort* Wn_pad = (ushort*)alloc((size_t)128 * 512 * 2);
  float*  bias2  = (float*) alloc(1024 * 4);
  float*  bc     = (float*) alloc(1024 * 4);
  float*  zbias  = (float*) alloc(128 * 4);
  ushort* xp     = (ushort*)alloc((size_t)N_NODES * 128 * 2);   // 8 MB
  ushort* WnpT   = (ushort*)alloc((size_t)512 * 128 * 2);
  float*  bnf    = (float*) alloc(512 * 4);
  float*  wf     = (float*) alloc(512 * 4);
  int*    flag   = (int*)   alloc(256);

  detect_dtype<<<1, 256, 0, stream>>>((const uint*)x, flag);
  prep_all<<<2564 + (N_NODES * 128) / 256, 256, 0, stream>>>(
      Wa, Wn, ba, bn, aw, x, flag, W2T, WnpT, Wn_pad, bias2, bnf, wf, zbias, xp);
  build_bc<<<256, 256, 0, stream>>>(W2T, bnf, bias2, bc);
  // WcT[1024][128] = W2T[1024][512] @ Wn_pad^T  (Wc = Wn_pad @ W2)
  {
    dim3 g(128 / 128, 1024 / 128);
    gemm_bf16<<<g, 256, 0, stream>>>(W2T, Wn_pad, zbias, WcT, 1024, 128, 512);
  }

  // CSR over dst
  hipMemsetAsync(cnt, 0, (size_t)N_NODES * 4, stream);
  csr_count<<<N_EDGES / 256, 256, 0, stream>>>(dst, cnt);
  csr_scan<<<1, 1024, 0, stream>>>(cnt, rowptr, cursor);
  csr_fill<<<N_EDGES / 256, 256, 0, stream>>>(dst, cursor, eidx);

  // h0 = xp @ Wnp + bn   (needed as aggregation input)
  {
    dim3 g(512 / 128, N_NODES / 128);
    gemm_bf16<<<g, 256, 0, stream>>>(xp, WnpT, bnf, hbA, N_NODES, 512, 128);
  }

  // layer 1: PQ = xp @ Wc + bc   (folded, K=128)
  {
    dim3 g(1024 / 128, N_NODES / 128);
    gemm_bf16<<<g, 256, 0, stream>>>(xp, WcT, bc, PQ, N_NODES, 1024, 128);
  }
  node_fused<<<N_NODES / 4, 256, 0, stream>>>(PQ, hbA, src, eidx, rowptr, wf, flag,
                                              hbB, d_out, 0);

  // layer 2: PQ = h1 @ W2 + bias2   (K=512)
  {
    dim3 g(1024 / 128, N_NODES / 128);
    gemm_bf16<<<g, 256, 0, stream>>>(hbB, W2T, bias2, PQ, N_NODES, 1024, 512);
  }
  node_fused<<<N_NODES / 4, 256, 0, stream>>>(PQ, hbB, src, eidx, rowptr, wf, flag,
                                              hbA, d_out, 1);
}